// Round 3
// baseline (411.241 us; speedup 1.0000x reference)
//
#include <hip/hip_runtime.h>
#include <math.h>
#include <stdint.h>

#define EPSQ 1e-5f
#define WELEM 262144          // 512*512
#define OUT0N 2097152         // 4*1024*512

// ---- workspace byte offsets (all level tensors bf16) ----
#define O_WSUMP  0                        // float[256] per-block partial sum(W)   (64/weight)
#define O_WABSP  1024                     // float[256] per-block partial sum|W|
#define O_MN     2048                     // float      global min(attn) (uint-bits atomicMin)
#define O_COLSUM 2112                     // float[2048] colsum of V-levels per (bh,dd)
#define O_CNT    10304                    // uint[64]   outg row-group completion counters
#define O_WSIGNS 16384                    // bf16[4*262144] (2 MB)
#define O_QLV    (O_WSIGNS + 8*WELEM)     // bf16[4096*512] q levels (4 MB)
#define O_CTXQ   O_QLV                    // bf16 ctx levels (overlays qlv: disjoint lifetime)
#define O_KLV    (O_QLV + 4194304)        // bf16 k levels
#define O_VLV    (O_KLV + 4194304)        // bf16 v levels
#define O_KQ     (O_VLV + 4194304)        // bf16[32*1024*64] per-head q levels
#define O_KK     (O_KQ + 4194304)
#define O_VT     (O_KK + 4194304)         // bf16[32][64][1024] V transposed
#define O_RMAX   (O_VT + 4194304)         // float[32768]
#define O_RSUM   (O_RMAX + 131072)        // float[32768]
#define O_OUTB   (O_RSUM + 131072)        // float[2097152] y = q + out (8 MB)

#define AS 72  // LDS row stride in bf16 elems: 144 B, 16B-aligned, conflict-benign

typedef __bf16 bf16x8 __attribute__((ext_vector_type(8)));
typedef __bf16 bf16x4 __attribute__((ext_vector_type(4)));
typedef float  floatx4 __attribute__((ext_vector_type(4)));

struct pre2 { bf16x8 lo, hi; };
__device__ __forceinline__ pre2 ldb16(const __bf16* p) {
  pre2 r; r.lo = *(const bf16x8*)p; r.hi = *(const bf16x8*)(p + 8); return r;
}
__device__ __forceinline__ void stb16(__bf16* p, pre2 r) {
  *(bf16x8*)p = r.lo; *(bf16x8*)(p + 8) = r.hi;
}

__device__ __forceinline__ float clampf(float x, float lo, float hi) {
  return fminf(fmaxf(x, lo), hi);
}

// ---------------- weight stats (atomic-free partials) + init duties ----------------
__global__ void k_wstats(const float* Wq, const float* Wk, const float* Wv, const float* Wo,
                         float* wsum_part, float* wabs_part,
                         float* colsum, unsigned int* mnbits, unsigned int* cnt) {
  __shared__ float s1[256], s2[256];
  int w = blockIdx.x >> 6;
  const float* W = (w == 0) ? Wq : (w == 1) ? Wk : (w == 2) ? Wv : Wo;
  int base = (blockIdx.x & 63) * 4096;
  float s = 0.f, sa = 0.f;
  for (int i = threadIdx.x; i < 4096; i += 256) {
    float x = W[base + i];
    s += x; sa += fabsf(x);
  }
  s1[threadIdx.x] = s; s2[threadIdx.x] = sa; __syncthreads();
  for (int o = 128; o > 0; o >>= 1) {
    if (threadIdx.x < o) { s1[threadIdx.x] += s1[threadIdx.x + o]; s2[threadIdx.x] += s2[threadIdx.x + o]; }
    __syncthreads();
  }
  if (threadIdx.x == 0) { wsum_part[blockIdx.x] = s1[0]; wabs_part[blockIdx.x] = s2[0]; }
  if (blockIdx.x == 0) {
    for (int i = threadIdx.x; i < 2048; i += 256) colsum[i] = 0.f;
    if (threadIdx.x < 64) cnt[threadIdx.x] = 0u;
    if (threadIdx.x == 0) mnbits[0] = 0x7f800000u;   // +inf
  }
}

// ---- merged: binarize weights (float4) + pre-quantize activations (bf16x8) ----
// y==0: sign pass (1024 blocks x 256 thr x 4 elems); y==1..3: act quant for q/k/v
__global__ __launch_bounds__(256) void k_signqx(
    const float* Wq, const float* Wk, const float* Wv, const float* Wo,
    const float* wsum_part,
    const float* q, const float* kin, const float* vin,
    const float* aq, const float* ak, const float* av,
    __bf16* wsigns, __bf16* qlv, __bf16* klv, __bf16* vlv) {
  int y = blockIdx.y;
  if (y == 0) {
    int idx = (blockIdx.x * 256 + threadIdx.x) * 4;
    int w = idx >> 18;
    const float* W = (w == 0) ? Wq : (w == 1) ? Wk : (w == 2) ? Wv : Wo;
    float s = 0.f;
#pragma unroll
    for (int i = 0; i < 64; ++i) s += wsum_part[w * 64 + i];
    float e = s * (1.0f / 262144.0f);
    float4 x = *(const float4*)&W[idx & (WELEM - 1)];
    bf16x4 o = { (__bf16)(float)((x.x > e) - (x.x < e)),
                 (__bf16)(float)((x.y > e) - (x.y < e)),
                 (__bf16)(float)((x.z > e) - (x.z < e)),
                 (__bf16)(float)((x.w > e) - (x.w < e)) };
    *(bf16x4*)&wsigns[idx] = o;
  } else {
    int z = y - 1;
    const float* X = (z == 0) ? q : (z == 1) ? kin : vin;
    const float* ap = (z == 0) ? aq : (z == 1) ? ak : av;
    __bf16* O = (z == 0) ? qlv : (z == 1) ? klv : vlv;
    float a = fmaxf(ap[0], EPSQ);
    size_t i = ((size_t)blockIdx.x * 256 + threadIdx.x) * 8;
    float4 x0 = *(const float4*)&X[i];
    float4 x1 = *(const float4*)&X[i + 4];
    bf16x8 o = { (__bf16)clampf(rintf(x0.x / a), -8.f, 7.f),
                 (__bf16)clampf(rintf(x0.y / a), -8.f, 7.f),
                 (__bf16)clampf(rintf(x0.z / a), -8.f, 7.f),
                 (__bf16)clampf(rintf(x0.w / a), -8.f, 7.f),
                 (__bf16)clampf(rintf(x1.x / a), -8.f, 7.f),
                 (__bf16)clampf(rintf(x1.y / a), -8.f, 7.f),
                 (__bf16)clampf(rintf(x1.z / a), -8.f, 7.f),
                 (__bf16)clampf(rintf(x1.w / a), -8.f, 7.f) };
    *(bf16x8*)&O[i] = o;
  }
}

// ---- projection: pipelined bf16 MFMA GEMM + head quant -> bf16 levels ----
// z==2 (V) writes transposed layout directly + float colsum atomics.
__global__ __launch_bounds__(256) void k_proj(
    const __bf16* qlv, const __bf16* klv, const __bf16* vlv,
    const float* bq, const float* bk, const float* bv,
    const float* aq, const float* ak, const float* av,
    const float* acq, const float* ack, const float* acv,
    const __bf16* wsigns, const float* wabs_part,
    __bf16* kqo, __bf16* kko, __bf16* vto, float* colsum) {
  __shared__ __align__(16) __bf16 As[64][AS];
  __shared__ __align__(16) __bf16 Bs[64][AS];
  int z = blockIdx.z;
  const __bf16* X   = (z == 0) ? qlv : (z == 1) ? klv : vlv;
  const float* bias = (z == 0) ? bq  : (z == 1) ? bk  : bv;
  const float* aip  = (z == 0) ? aq  : (z == 1) ? ak  : av;
  const float* ahp  = (z == 0) ? acq : (z == 1) ? ack : acv;
  float a_in = fmaxf(aip[0], EPSQ);
  float a_hd = fmaxf(ahp[0], EPSQ);
  float sa = 0.f;
#pragma unroll
  for (int i = 0; i < 64; ++i) sa += wabs_part[z * 64 + i];
  float m_w  = sa * (1.0f / 262144.0f);
  const __bf16* S = wsigns + (size_t)z * WELEM;

  int n0 = blockIdx.x * 64;
  int f0 = blockIdx.y * 64;
  int t = threadIdx.x;
  int lane = t & 63, w = t >> 6, quad = lane >> 4, l16 = lane & 15;
  int e16 = (t & 3) * 16, mrow = t >> 2;
  const __bf16* ap = &X[(size_t)(n0 + mrow) * 512 + e16];
  const __bf16* bp = &S[(size_t)(f0 + mrow) * 512 + e16];
  floatx4 acc[4];
#pragma unroll
  for (int nt = 0; nt < 4; ++nt) acc[nt] = (floatx4){0.f, 0.f, 0.f, 0.f};

  pre2 pa = ldb16(ap), pb = ldb16(bp);
  for (int k0 = 0; k0 < 512; k0 += 64) {
    if (k0) __syncthreads();
    stb16(&As[mrow][e16], pa);
    stb16(&Bs[mrow][e16], pb);
    if (k0 + 64 < 512) { pa = ldb16(ap + k0 + 64); pb = ldb16(bp + k0 + 64); }
    __syncthreads();
#pragma unroll
    for (int kh = 0; kh < 64; kh += 32) {
      bf16x8 a = *(const bf16x8*)&As[w * 16 + l16][kh + quad * 8];
#pragma unroll
      for (int nt = 0; nt < 4; ++nt) {
        bf16x8 b = *(const bf16x8*)&Bs[nt * 16 + l16][kh + quad * 8];
        acc[nt] = __builtin_amdgcn_mfma_f32_16x16x32_bf16(a, b, acc[nt], 0, 0, 0);
      }
    }
  }
  float s_am = a_in * m_w;
  if (z != 2) {
    __bf16* outp = (z == 0) ? kqo : kko;
#pragma unroll
    for (int nt = 0; nt < 4; ++nt) {
      int f = f0 + nt * 16 + l16;
      int h = f >> 6, dd = f & 63;
      float bia = bias[f];
#pragma unroll
      for (int r = 0; r < 4; ++r) {
        int n = n0 + w * 16 + quad * 4 + r;
        int b = n >> 10, srow = n & 1023;
        float P = s_am * acc[nt][r] + bia;
        float hq = clampf(rintf(P / a_hd), -8.f, 7.f);
        outp[(size_t)((b * 8 + h) * 1024 + srow) * 64 + dd] = (__bf16)hq;
      }
    }
  } else {
    int b = n0 >> 10;                    // 64-row strip never crosses a batch boundary
    int srow0 = (n0 & 1023) + w * 16 + quad * 4;
#pragma unroll
    for (int nt = 0; nt < 4; ++nt) {
      int f = f0 + nt * 16 + l16;
      int h = f >> 6, dd = f & 63;
      int bh = b * 8 + h;
      float bia = bias[f];
      float part = 0.f;
      bf16x4 pack;
#pragma unroll
      for (int r = 0; r < 4; ++r) {
        float P = s_am * acc[nt][r] + bia;
        float hq = clampf(rintf(P / a_hd), -8.f, 7.f);
        pack[r] = (__bf16)hq;
        part += hq;
      }
      *(bf16x4*)&vto[((size_t)bh * 64 + dd) * 1024 + srow0] = pack;
      atomicAdd(&colsum[bh * 64 + dd], part);   // integer-valued floats: exact
    }
  }
}

// ------- fused QK^T + online row stats + global-min atomic, pipelined B tiles -------
// scores stores are non-temporal: written once, never re-read on device.
__global__ __launch_bounds__(256) void k_qks(
    const __bf16* kq, const __bf16* kkv,
    const float* acq, const float* ack,
    float* scores, float* rmax, float* rsum, unsigned int* mnbits) {
  __shared__ __align__(16) __bf16 As[64][AS];
  __shared__ __align__(16) __bf16 Bs[64][AS];
  __shared__ float redmin[16];
  int bh = blockIdx.y;
  int q0 = blockIdx.x * 64;
  const __bf16* A  = kq  + (size_t)bh * 65536;
  const __bf16* Bp = kkv + (size_t)bh * 65536;
  float* Sp = scores + ((size_t)bh * 1024 + q0) * 1024;
  int t = threadIdx.x;
  int lane = t & 63, w = t >> 6, quad = lane >> 4, l16 = lane & 15;
  int e16 = (t & 3) * 16, mrow = t >> 2;
  float sc = fmaxf(acq[0], EPSQ) * fmaxf(ack[0], EPSQ) * 0.125f;  // /sqrt(64)

  stb16(&As[mrow][e16], ldb16(&A[(q0 + mrow) * 64 + e16]));  // stage A once
  float m_run[4], l_run[4], mn_run[4];
#pragma unroll
  for (int rr = 0; rr < 4; ++rr) { m_run[rr] = -INFINITY; l_run[rr] = 0.f; mn_run[rr] = INFINITY; }

  pre2 pb = ldb16(&Bp[mrow * 64 + e16]);
  for (int ct = 0; ct < 16; ++ct) {
    if (ct) __syncthreads();
    stb16(&Bs[mrow][e16], pb);
    if (ct < 15) pb = ldb16(&Bp[((ct + 1) * 64 + mrow) * 64 + e16]);
    __syncthreads();
    floatx4 acc[4];
#pragma unroll
    for (int nt = 0; nt < 4; ++nt) acc[nt] = (floatx4){0.f, 0.f, 0.f, 0.f};
#pragma unroll
    for (int kh = 0; kh < 64; kh += 32) {
      bf16x8 a = *(const bf16x8*)&As[w * 16 + l16][kh + quad * 8];
#pragma unroll
      for (int nt = 0; nt < 4; ++nt) {
        bf16x8 b = *(const bf16x8*)&Bs[nt * 16 + l16][kh + quad * 8];
        acc[nt] = __builtin_amdgcn_mfma_f32_16x16x32_bf16(a, b, acc[nt], 0, 0, 0);
      }
    }
#pragma unroll
    for (int rr = 0; rr < 4; ++rr) {
      int row = w * 16 + quad * 4 + rr;
      float v[4];
#pragma unroll
      for (int nt = 0; nt < 4; ++nt) {
        v[nt] = sc * acc[nt][rr];
        __builtin_nontemporal_store(v[nt], &Sp[(size_t)row * 1024 + ct * 64 + nt * 16 + l16]);
      }
      float tmax = fmaxf(fmaxf(v[0], v[1]), fmaxf(v[2], v[3]));
      float tmin = fminf(fminf(v[0], v[1]), fminf(v[2], v[3]));
      mn_run[rr] = fminf(mn_run[rr], tmin);
      float mnew = fmaxf(m_run[rr], tmax);
      float s = 0.f;
#pragma unroll
      for (int nt = 0; nt < 4; ++nt) s += expf(v[nt] - mnew);
      l_run[rr] = l_run[rr] * expf(m_run[rr] - mnew) + s;
      m_run[rr] = mnew;
    }
  }
#pragma unroll
  for (int o = 1; o < 16; o <<= 1) {
#pragma unroll
    for (int rr = 0; rr < 4; ++rr) {
      float mo = __shfl_xor(m_run[rr], o);
      float lo = __shfl_xor(l_run[rr], o);
      float mnew = fmaxf(m_run[rr], mo);
      l_run[rr] = l_run[rr] * expf(m_run[rr] - mnew) + lo * expf(mo - mnew);
      m_run[rr] = mnew;
      mn_run[rr] = fminf(mn_run[rr], __shfl_xor(mn_run[rr], o));
    }
  }
  if (l16 == 0) {
    float cand = INFINITY;
#pragma unroll
    for (int rr = 0; rr < 4; ++rr) {
      int r = bh * 1024 + q0 + w * 16 + quad * 4 + rr;
      rmax[r] = m_run[rr];
      rsum[r] = l_run[rr];
      cand = fminf(cand, expf(mn_run[rr] - m_run[rr]) * (1.0f / l_run[rr]));
    }
    redmin[w * 4 + quad] = cand;
  }
  __syncthreads();
  if (t == 0) {
    float c = redmin[0];
#pragma unroll
    for (int i = 1; i < 16; ++i) c = fminf(c, redmin[i]);
    // candidates are strictly positive floats -> uint order == float order
    atomicMin(mnbits, __float_as_uint(c));
  }
}

// ------- pass 2: recompute QK^T (bitwise == pass 1), softmax+uns4, PV MFMA, sig8 -------
__global__ __launch_bounds__(256) void k_pv(
    const __bf16* kq, const __bf16* kkv,
    const float* rmax, const float* rsum,
    const float* mnf, const float* colsum, const __bf16* vt,
    const float* acq, const float* ack,
    const float* acattn, const float* acv, const float* ao,
    __bf16* ctxq) {
  __shared__ __align__(16) __bf16 Ks[64][AS];
  __shared__ __align__(16) __bf16 Vs[64][AS];
  __shared__ __align__(16) __bf16 As[32][AS];
  int bh = blockIdx.y;
  int m0 = blockIdx.x * 32;
  float mn    = mnf[0];                    // bits written by atomicMin = min float
  float a_att = fmaxf(acattn[0], EPSQ);
  float a_v   = fmaxf(acv[0], EPSQ);
  float a_o   = fmaxf(ao[0], EPSQ);
  float sc    = fmaxf(acq[0], EPSQ) * fmaxf(ack[0], EPSQ) * 0.125f;  // same as pass 1
  const __bf16* Qp = kq  + (size_t)bh * 65536;
  const __bf16* Kp = kkv + (size_t)bh * 65536;
  const __bf16* Vt = vt  + (size_t)bh * 65536;
  int t = threadIdx.x;
  int lane = t & 63, w = t >> 6, quad = lane >> 4, l16 = lane & 15;
  int e16 = (t & 3) * 16, mrow = t >> 2;
  int mt = w & 1, np = w >> 1;

  // Q fragments held in registers for the whole kernel (A-operand of QK^T)
  bf16x8 qa[2][2];
#pragma unroll
  for (int mh = 0; mh < 2; ++mh)
#pragma unroll
    for (int kh2 = 0; kh2 < 2; ++kh2)
      qa[mh][kh2] = *(const bf16x8*)&Qp[(size_t)(m0 + mh * 16 + l16) * 64 + kh2 * 32 + quad * 8];

  // row stats for the rows this thread produces in QK^T C-layout
  float rm[2][4], inv[2][4];
#pragma unroll
  for (int mh = 0; mh < 2; ++mh)
#pragma unroll
    for (int r = 0; r < 4; ++r) {
      int rr = bh * 1024 + m0 + mh * 16 + quad * 4 + r;
      rm[mh][r]  = rmax[rr];
      inv[mh][r] = 1.0f / rsum[rr];
    }

  floatx4 acc[2];
  acc[0] = (floatx4){0.f, 0.f, 0.f, 0.f};
  acc[1] = (floatx4){0.f, 0.f, 0.f, 0.f};

  pre2 kpre = ldb16(&Kp[(size_t)mrow * 64 + e16]);
  pre2 vpre = ldb16(&Vt[(size_t)mrow * 1024 + e16]);
  for (int ct = 0; ct < 16; ++ct) {
    if (ct) __syncthreads();
    stb16(&Ks[mrow][e16], kpre);
    stb16(&Vs[mrow][e16], vpre);
    if (ct < 15) {
      kpre = ldb16(&Kp[(size_t)((ct + 1) * 64 + mrow) * 64 + e16]);
      vpre = ldb16(&Vt[(size_t)mrow * 1024 + (ct + 1) * 64 + e16]);
    }
    __syncthreads();
    // QK^T: wave w owns k-cols ct*64 + w*16 + l16, rows m0..m0+31
    floatx4 s2[2];
    s2[0] = (floatx4){0.f, 0.f, 0.f, 0.f};
    s2[1] = (floatx4){0.f, 0.f, 0.f, 0.f};
#pragma unroll
    for (int kh2 = 0; kh2 < 2; ++kh2) {
      bf16x8 b = *(const bf16x8*)&Ks[w * 16 + l16][kh2 * 32 + quad * 8];
#pragma unroll
      for (int mh = 0; mh < 2; ++mh)
        s2[mh] = __builtin_amdgcn_mfma_f32_16x16x32_bf16(qa[mh][kh2], b, s2[mh], 0, 0, 0);
    }
    // softmax + uns4 quant -> LDS attn-levels tile (same arithmetic chain as pass 1)
#pragma unroll
    for (int mh = 0; mh < 2; ++mh)
#pragma unroll
      for (int r = 0; r < 4; ++r) {
        float p = expf(sc * s2[mh][r] - rm[mh][r]) * inv[mh][r];
        As[mh * 16 + quad * 4 + r][w * 16 + l16] =
            (__bf16)clampf(rintf((p - mn) / a_att), 0.f, 15.f);
      }
    __syncthreads();
    // PV
#pragma unroll
    for (int kh = 0; kh < 64; kh += 32) {
      bf16x8 a = *(const bf16x8*)&As[mt * 16 + l16][kh + quad * 8];
#pragma unroll
      for (int j = 0; j < 2; ++j) {
        bf16x8 b = *(const bf16x8*)&Vs[(np * 2 + j) * 16 + l16][kh + quad * 8];
        acc[j] = __builtin_amdgcn_mfma_f32_16x16x32_bf16(a, b, acc[j], 0, 0, 0);
      }
    }
  }
  float scf = a_att * a_v;
  float mnv = mn * a_v;
  int b = bh >> 3, h = bh & 7;
#pragma unroll
  for (int j = 0; j < 2; ++j) {
    int dd = (np * 2 + j) * 16 + l16;
    float cs = colsum[bh * 64 + dd];
#pragma unroll
    for (int r = 0; r < 4; ++r) {
      int srow = m0 + mt * 16 + quad * 4 + r;
      float ctx = scf * acc[j][r] + mnv * cs;
      float c8 = clampf(rintf(ctx / a_o), -128.f, 127.f);
      ctxq[(size_t)b * 524288 + (size_t)(h * 128 + (srow >> 3)) * 512 + (srow & 7) * 64 + dd] = (__bf16)c8;
    }
  }
}

// ---- output projection MFMA + fused q-add + last-finisher LayerNorm -> out0 ----
// Each (n0,f0) block writes y = q + out tile; the 8th finisher of each 64-row
// group performs LN for those rows (reads L2/L3-hot y). Removes the k_ln launch.
__global__ __launch_bounds__(256) void k_outg(
    const __bf16* ctxq, const __bf16* signs_o,
    const float* wabs_part, const float* ao,
    const float* q, const float* lng, const float* lnb,
    float* outb, unsigned int* cnt, float* out0) {
  __shared__ __align__(16) __bf16 As[64][AS];
  __shared__ __align__(16) __bf16 Bs[64][AS];
  __shared__ unsigned int oldc;
  int n0 = blockIdx.x * 64, f0 = blockIdx.y * 64;
  int t = threadIdx.x;
  int lane = t & 63, w = t >> 6, quad = lane >> 4, l16 = lane & 15;
  int e16 = (t & 3) * 16, mrow = t >> 2;
  const __bf16* ap = &ctxq[(size_t)(n0 + mrow) * 512 + e16];
  const __bf16* bp = &signs_o[(size_t)(f0 + mrow) * 512 + e16];
  floatx4 acc[4];
#pragma unroll
  for (int nt = 0; nt < 4; ++nt) acc[nt] = (floatx4){0.f, 0.f, 0.f, 0.f};
  pre2 pa = ldb16(ap), pb = ldb16(bp);
  for (int k0 = 0; k0 < 512; k0 += 64) {
    if (k0) __syncthreads();
    stb16(&As[mrow][e16], pa);
    stb16(&Bs[mrow][e16], pb);
    if (k0 + 64 < 512) { pa = ldb16(ap + k0 + 64); pb = ldb16(bp + k0 + 64); }
    __syncthreads();
#pragma unroll
    for (int kh = 0; kh < 64; kh += 32) {
      bf16x8 a = *(const bf16x8*)&As[w * 16 + l16][kh + quad * 8];
#pragma unroll
      for (int nt = 0; nt < 4; ++nt) {
        bf16x8 b = *(const bf16x8*)&Bs[nt * 16 + l16][kh + quad * 8];
        acc[nt] = __builtin_amdgcn_mfma_f32_16x16x32_bf16(a, b, acc[nt], 0, 0, 0);
      }
    }
  }
  float sa = 0.f;
#pragma unroll
  for (int i = 0; i < 64; ++i) sa += wabs_part[3 * 64 + i];
  float scale = fmaxf(ao[0], EPSQ) * (sa * (1.0f / 262144.0f));
#pragma unroll
  for (int nt = 0; nt < 4; ++nt)
#pragma unroll
    for (int r = 0; r < 4; ++r) {
      size_t idx = (size_t)(n0 + w * 16 + quad * 4 + r) * 512 + f0 + nt * 16 + l16;
      outb[idx] = q[idx] + scale * acc[nt][r];
    }
  // ---- completion handshake (deadlock-free, no cooperative launch) ----
  __threadfence();                       // release: y tile visible device-wide
  __syncthreads();                       // all threads' stores precede the count
  if (t == 0) oldc = atomicAdd(&cnt[blockIdx.x], 1);
  __syncthreads();
  if (oldc != 7) return;                 // uniform exit for non-finishers
  __threadfence();                       // acquire: other tiles' y now readable
  // ---- LN for rows n0..n0+63: 4 threads per row, 128 cols each ----
  int r0 = n0 + (t >> 2);
  int qd = t & 3;
  const float* yp = outb + (size_t)r0 * 512 + qd * 128;
  float s = 0.f, s2 = 0.f;
#pragma unroll
  for (int i = 0; i < 128; i += 4) {
    float4 v4 = *(const float4*)&yp[i];
    s  += v4.x + v4.y + v4.z + v4.w;
    s2 += v4.x * v4.x + v4.y * v4.y + v4.z * v4.z + v4.w * v4.w;
  }
  // combine the 4 quarter-partials (threads r*4+qd are consecutive lanes)
  s  += __shfl_xor(s, 1);  s  += __shfl_xor(s, 2);
  s2 += __shfl_xor(s2, 1); s2 += __shfl_xor(s2, 2);
  float mu  = s * (1.0f / 512.0f);
  float var = s2 * (1.0f / 512.0f) - mu * mu;
  float den = sqrtf(var + 1e-5f);
  float* op = out0 + (size_t)r0 * 512 + qd * 128;
  const float* gp = lng + qd * 128;
  const float* bbp = lnb + qd * 128;
#pragma unroll
  for (int i = 0; i < 128; i += 4) {
    float4 v4 = *(const float4*)&yp[i];
    float4 g4 = *(const float4*)&gp[i];
    float4 b4 = *(const float4*)&bbp[i];
    float4 o;
    o.x = (v4.x - mu) / den * g4.x + b4.x;
    o.y = (v4.y - mu) / den * g4.y + b4.y;
    o.z = (v4.z - mu) / den * g4.z + b4.z;
    o.w = (v4.w - mu) / den * g4.w + b4.w;
    *(float4*)&op[i] = o;
  }
}

extern "C" void kernel_launch(void* const* d_in, const int* in_sizes, int n_in,
                              void* d_out, int out_size, void* d_ws, size_t ws_size,
                              hipStream_t stream) {
  const float* q   = (const float*)d_in[0];
  const float* k   = (const float*)d_in[1];
  const float* v   = (const float*)d_in[2];
  // d_in[3] = mask (int32) — structurally unused by the reference
  const float* Wq  = (const float*)d_in[4];
  const float* Wk  = (const float*)d_in[5];
  const float* Wv  = (const float*)d_in[6];
  const float* Wo  = (const float*)d_in[7];
  const float* bq  = (const float*)d_in[8];
  const float* bk  = (const float*)d_in[9];
  const float* bv  = (const float*)d_in[10];
  const float* lng = (const float*)d_in[11];
  const float* lnb = (const float*)d_in[12];
  const float* aq  = (const float*)d_in[13];
  const float* ak  = (const float*)d_in[14];
  const float* av  = (const float*)d_in[15];
  const float* acq = (const float*)d_in[16];
  const float* ack = (const float*)d_in[17];
  const float* acv = (const float*)d_in[18];
  const float* aca = (const float*)d_in[19];
  const float* ao  = (const float*)d_in[20];

  char* ws = (char*)d_ws;
  float*  wsum_p = (float*)(ws + O_WSUMP);
  float*  wabs_p = (float*)(ws + O_WABSP);
  float*  mnf    = (float*)(ws + O_MN);
  float*  colsum = (float*)(ws + O_COLSUM);
  unsigned int* cnt = (unsigned int*)(ws + O_CNT);
  __bf16* wsigns = (__bf16*)(ws + O_WSIGNS);
  __bf16* qlv    = (__bf16*)(ws + O_QLV);
  __bf16* klv    = (__bf16*)(ws + O_KLV);
  __bf16* vlv    = (__bf16*)(ws + O_VLV);
  __bf16* kqb    = (__bf16*)(ws + O_KQ);
  __bf16* kkb    = (__bf16*)(ws + O_KK);
  __bf16* vtb    = (__bf16*)(ws + O_VT);
  float*  rmax   = (float*)(ws + O_RMAX);
  float*  rsum   = (float*)(ws + O_RSUM);
  __bf16* ctxq   = (__bf16*)(ws + O_CTXQ);
  float*  outb   = (float*)(ws + O_OUTB);

  float* out0   = (float*)d_out;
  float* scores = (float*)d_out + OUT0N;

  k_wstats<<<256, 256, 0, stream>>>(Wq, Wk, Wv, Wo, wsum_p, wabs_p, colsum,
                                    (unsigned int*)mnf, cnt);
  k_signqx<<<dim3(1024, 4), 256, 0, stream>>>(Wq, Wk, Wv, Wo, wsum_p,
                                              q, k, v, aq, ak, av,
                                              wsigns, qlv, klv, vlv);
  k_proj<<<dim3(64, 8, 3), 256, 0, stream>>>(qlv, klv, vlv, bq, bk, bv, aq, ak, av,
                                             acq, ack, acv, wsigns, wabs_p,
                                             kqb, kkb, vtb, colsum);
  k_qks<<<dim3(16, 32), 256, 0, stream>>>(kqb, kkb, acq, ack, scores, rmax, rsum,
                                          (unsigned int*)mnf);
  k_pv<<<dim3(32, 32), 256, 0, stream>>>(kqb, kkb, rmax, rsum, mnf, colsum, vtb,
                                         acq, ack, aca, acv, ao, ctxq);
  k_outg<<<dim3(64, 8), 256, 0, stream>>>(ctxq, wsigns + 3 * WELEM, wabs_p, ao,
                                          q, lng, lnb, outb, cnt, out0);
}

// Round 4
// 336.033 us; speedup vs baseline: 1.2238x; 1.2238x over previous
//
#include <hip/hip_runtime.h>
#include <math.h>
#include <stdint.h>

#define EPSQ 1e-5f
#define WELEM 262144          // 512*512
#define OUT0N 2097152         // 4*1024*512

// ---- workspace byte offsets (all level tensors bf16) ----
#define O_WSUMP  0                        // float[256] per-block partial sum(W)   (64/weight)
#define O_WABSP  1024                     // float[256] per-block partial sum|W|
#define O_MN     2048                     // float      global min(attn) (uint-bits atomicMin)
#define O_COLSUM 2112                     // float[2048] colsum of V-levels per (bh,dd)
#define O_WSIGNS 16384                    // bf16[4*262144] (2 MB)
#define O_QLV    (O_WSIGNS + 8*WELEM)     // bf16[4096*512] q levels (4 MB)
#define O_CTXQ   O_QLV                    // bf16 ctx levels (overlays qlv: disjoint lifetime)
#define O_KLV    (O_QLV + 4194304)        // bf16 k levels
#define O_VLV    (O_KLV + 4194304)        // bf16 v levels
#define O_KQ     (O_VLV + 4194304)        // bf16[32*1024*64] per-head q levels
#define O_KK     (O_KQ + 4194304)
#define O_VT     (O_KK + 4194304)         // bf16[32][64][1024] V transposed
#define O_RMAX   (O_VT + 4194304)         // float[32768]
#define O_RSUM   (O_RMAX + 131072)        // float[32768]
#define O_OUTB   (O_RSUM + 131072)        // float[2097152] out before LN (8 MB)

#define AS 72  // LDS row stride in bf16 elems: 144 B, 16B-aligned, conflict-benign

typedef __bf16 bf16x8 __attribute__((ext_vector_type(8)));
typedef __bf16 bf16x4 __attribute__((ext_vector_type(4)));
typedef float  floatx4 __attribute__((ext_vector_type(4)));

struct pre2 { bf16x8 lo, hi; };
__device__ __forceinline__ pre2 ldb16(const __bf16* p) {
  pre2 r; r.lo = *(const bf16x8*)p; r.hi = *(const bf16x8*)(p + 8); return r;
}
__device__ __forceinline__ void stb16(__bf16* p, pre2 r) {
  *(bf16x8*)p = r.lo; *(bf16x8*)(p + 8) = r.hi;
}

__device__ __forceinline__ float clampf(float x, float lo, float hi) {
  return fminf(fmaxf(x, lo), hi);
}

// ---------------- weight stats (atomic-free partials) + init duties ----------------
__global__ void k_wstats(const float* Wq, const float* Wk, const float* Wv, const float* Wo,
                         float* wsum_part, float* wabs_part,
                         float* colsum, unsigned int* mnbits) {
  __shared__ float s1[256], s2[256];
  int w = blockIdx.x >> 6;
  const float* W = (w == 0) ? Wq : (w == 1) ? Wk : (w == 2) ? Wv : Wo;
  int base = (blockIdx.x & 63) * 4096;
  float s = 0.f, sa = 0.f;
  for (int i = threadIdx.x; i < 4096; i += 256) {
    float x = W[base + i];
    s += x; sa += fabsf(x);
  }
  s1[threadIdx.x] = s; s2[threadIdx.x] = sa; __syncthreads();
  for (int o = 128; o > 0; o >>= 1) {
    if (threadIdx.x < o) { s1[threadIdx.x] += s1[threadIdx.x + o]; s2[threadIdx.x] += s2[threadIdx.x + o]; }
    __syncthreads();
  }
  if (threadIdx.x == 0) { wsum_part[blockIdx.x] = s1[0]; wabs_part[blockIdx.x] = s2[0]; }
  if (blockIdx.x == 0) {
    for (int i = threadIdx.x; i < 2048; i += 256) colsum[i] = 0.f;
    if (threadIdx.x == 0) mnbits[0] = 0x7f800000u;   // +inf
  }
}

// ---- merged: binarize weights (float4) + pre-quantize activations (bf16x8) ----
// y==0: sign pass (1024 blocks x 256 thr x 4 elems); y==1..3: act quant for q/k/v
__global__ __launch_bounds__(256) void k_signqx(
    const float* Wq, const float* Wk, const float* Wv, const float* Wo,
    const float* wsum_part,
    const float* q, const float* kin, const float* vin,
    const float* aq, const float* ak, const float* av,
    __bf16* wsigns, __bf16* qlv, __bf16* klv, __bf16* vlv) {
  int y = blockIdx.y;
  if (y == 0) {
    int idx = (blockIdx.x * 256 + threadIdx.x) * 4;
    int w = idx >> 18;
    const float* W = (w == 0) ? Wq : (w == 1) ? Wk : (w == 2) ? Wv : Wo;
    float s = 0.f;
#pragma unroll
    for (int i = 0; i < 64; ++i) s += wsum_part[w * 64 + i];
    float e = s * (1.0f / 262144.0f);
    float4 x = *(const float4*)&W[idx & (WELEM - 1)];
    bf16x4 o = { (__bf16)(float)((x.x > e) - (x.x < e)),
                 (__bf16)(float)((x.y > e) - (x.y < e)),
                 (__bf16)(float)((x.z > e) - (x.z < e)),
                 (__bf16)(float)((x.w > e) - (x.w < e)) };
    *(bf16x4*)&wsigns[idx] = o;
  } else {
    int z = y - 1;
    const float* X = (z == 0) ? q : (z == 1) ? kin : vin;
    const float* ap = (z == 0) ? aq : (z == 1) ? ak : av;
    __bf16* O = (z == 0) ? qlv : (z == 1) ? klv : vlv;
    float a = fmaxf(ap[0], EPSQ);
    size_t i = ((size_t)blockIdx.x * 256 + threadIdx.x) * 8;
    float4 x0 = *(const float4*)&X[i];
    float4 x1 = *(const float4*)&X[i + 4];
    bf16x8 o = { (__bf16)clampf(rintf(x0.x / a), -8.f, 7.f),
                 (__bf16)clampf(rintf(x0.y / a), -8.f, 7.f),
                 (__bf16)clampf(rintf(x0.z / a), -8.f, 7.f),
                 (__bf16)clampf(rintf(x0.w / a), -8.f, 7.f),
                 (__bf16)clampf(rintf(x1.x / a), -8.f, 7.f),
                 (__bf16)clampf(rintf(x1.y / a), -8.f, 7.f),
                 (__bf16)clampf(rintf(x1.z / a), -8.f, 7.f),
                 (__bf16)clampf(rintf(x1.w / a), -8.f, 7.f) };
    *(bf16x8*)&O[i] = o;
  }
}

// ---- projection: pipelined bf16 MFMA GEMM + head quant -> bf16 levels ----
// z==2 (V) writes transposed layout directly + float colsum atomics.
__global__ __launch_bounds__(256) void k_proj(
    const __bf16* qlv, const __bf16* klv, const __bf16* vlv,
    const float* bq, const float* bk, const float* bv,
    const float* aq, const float* ak, const float* av,
    const float* acq, const float* ack, const float* acv,
    const __bf16* wsigns, const float* wabs_part,
    __bf16* kqo, __bf16* kko, __bf16* vto, float* colsum) {
  __shared__ __align__(16) __bf16 As[64][AS];
  __shared__ __align__(16) __bf16 Bs[64][AS];
  int z = blockIdx.z;
  const __bf16* X   = (z == 0) ? qlv : (z == 1) ? klv : vlv;
  const float* bias = (z == 0) ? bq  : (z == 1) ? bk  : bv;
  const float* aip  = (z == 0) ? aq  : (z == 1) ? ak  : av;
  const float* ahp  = (z == 0) ? acq : (z == 1) ? ack : acv;
  float a_in = fmaxf(aip[0], EPSQ);
  float a_hd = fmaxf(ahp[0], EPSQ);
  float sa = 0.f;
#pragma unroll
  for (int i = 0; i < 64; ++i) sa += wabs_part[z * 64 + i];
  float m_w  = sa * (1.0f / 262144.0f);
  const __bf16* S = wsigns + (size_t)z * WELEM;

  int n0 = blockIdx.x * 64;
  int f0 = blockIdx.y * 64;
  int t = threadIdx.x;
  int lane = t & 63, w = t >> 6, quad = lane >> 4, l16 = lane & 15;
  int e16 = (t & 3) * 16, mrow = t >> 2;
  const __bf16* ap = &X[(size_t)(n0 + mrow) * 512 + e16];
  const __bf16* bp = &S[(size_t)(f0 + mrow) * 512 + e16];
  floatx4 acc[4];
#pragma unroll
  for (int nt = 0; nt < 4; ++nt) acc[nt] = (floatx4){0.f, 0.f, 0.f, 0.f};

  pre2 pa = ldb16(ap), pb = ldb16(bp);
  for (int k0 = 0; k0 < 512; k0 += 64) {
    if (k0) __syncthreads();
    stb16(&As[mrow][e16], pa);
    stb16(&Bs[mrow][e16], pb);
    if (k0 + 64 < 512) { pa = ldb16(ap + k0 + 64); pb = ldb16(bp + k0 + 64); }
    __syncthreads();
#pragma unroll
    for (int kh = 0; kh < 64; kh += 32) {
      bf16x8 a = *(const bf16x8*)&As[w * 16 + l16][kh + quad * 8];
#pragma unroll
      for (int nt = 0; nt < 4; ++nt) {
        bf16x8 b = *(const bf16x8*)&Bs[nt * 16 + l16][kh + quad * 8];
        acc[nt] = __builtin_amdgcn_mfma_f32_16x16x32_bf16(a, b, acc[nt], 0, 0, 0);
      }
    }
  }
  float s_am = a_in * m_w;
  if (z != 2) {
    __bf16* outp = (z == 0) ? kqo : kko;
#pragma unroll
    for (int nt = 0; nt < 4; ++nt) {
      int f = f0 + nt * 16 + l16;
      int h = f >> 6, dd = f & 63;
      float bia = bias[f];
#pragma unroll
      for (int r = 0; r < 4; ++r) {
        int n = n0 + w * 16 + quad * 4 + r;
        int b = n >> 10, srow = n & 1023;
        float P = s_am * acc[nt][r] + bia;
        float hq = clampf(rintf(P / a_hd), -8.f, 7.f);
        outp[(size_t)((b * 8 + h) * 1024 + srow) * 64 + dd] = (__bf16)hq;
      }
    }
  } else {
    int b = n0 >> 10;                    // 64-row strip never crosses a batch boundary
    int srow0 = (n0 & 1023) + w * 16 + quad * 4;
#pragma unroll
    for (int nt = 0; nt < 4; ++nt) {
      int f = f0 + nt * 16 + l16;
      int h = f >> 6, dd = f & 63;
      int bh = b * 8 + h;
      float bia = bias[f];
      float part = 0.f;
      bf16x4 pack;
#pragma unroll
      for (int r = 0; r < 4; ++r) {
        float P = s_am * acc[nt][r] + bia;
        float hq = clampf(rintf(P / a_hd), -8.f, 7.f);
        pack[r] = (__bf16)hq;
        part += hq;
      }
      *(bf16x4*)&vto[((size_t)bh * 64 + dd) * 1024 + srow0] = pack;
      atomicAdd(&colsum[bh * 64 + dd], part);   // integer-valued floats: exact
    }
  }
}

// ------- fused QK^T + online row stats + global-min atomic, pipelined B tiles -------
__global__ __launch_bounds__(256) void k_qks(
    const __bf16* kq, const __bf16* kkv,
    const float* acq, const float* ack,
    float* scores, float* rmax, float* rsum, unsigned int* mnbits) {
  __shared__ __align__(16) __bf16 As[64][AS];
  __shared__ __align__(16) __bf16 Bs[64][AS];
  __shared__ float redmin[16];
  int bh = blockIdx.y;
  int q0 = blockIdx.x * 64;
  const __bf16* A  = kq  + (size_t)bh * 65536;
  const __bf16* Bp = kkv + (size_t)bh * 65536;
  float* Sp = scores + ((size_t)bh * 1024 + q0) * 1024;
  int t = threadIdx.x;
  int lane = t & 63, w = t >> 6, quad = lane >> 4, l16 = lane & 15;
  int e16 = (t & 3) * 16, mrow = t >> 2;
  float sc = fmaxf(acq[0], EPSQ) * fmaxf(ack[0], EPSQ) * 0.125f;  // /sqrt(64)

  stb16(&As[mrow][e16], ldb16(&A[(q0 + mrow) * 64 + e16]));  // stage A once
  float m_run[4], l_run[4], mn_run[4];
#pragma unroll
  for (int rr = 0; rr < 4; ++rr) { m_run[rr] = -INFINITY; l_run[rr] = 0.f; mn_run[rr] = INFINITY; }

  pre2 pb = ldb16(&Bp[mrow * 64 + e16]);
  for (int ct = 0; ct < 16; ++ct) {
    if (ct) __syncthreads();
    stb16(&Bs[mrow][e16], pb);
    if (ct < 15) pb = ldb16(&Bp[((ct + 1) * 64 + mrow) * 64 + e16]);
    __syncthreads();
    floatx4 acc[4];
#pragma unroll
    for (int nt = 0; nt < 4; ++nt) acc[nt] = (floatx4){0.f, 0.f, 0.f, 0.f};
#pragma unroll
    for (int kh = 0; kh < 64; kh += 32) {
      bf16x8 a = *(const bf16x8*)&As[w * 16 + l16][kh + quad * 8];
#pragma unroll
      for (int nt = 0; nt < 4; ++nt) {
        bf16x8 b = *(const bf16x8*)&Bs[nt * 16 + l16][kh + quad * 8];
        acc[nt] = __builtin_amdgcn_mfma_f32_16x16x32_bf16(a, b, acc[nt], 0, 0, 0);
      }
    }
#pragma unroll
    for (int rr = 0; rr < 4; ++rr) {
      int row = w * 16 + quad * 4 + rr;
      float v[4];
#pragma unroll
      for (int nt = 0; nt < 4; ++nt) {
        v[nt] = sc * acc[nt][rr];
        Sp[(size_t)row * 1024 + ct * 64 + nt * 16 + l16] = v[nt];
      }
      float tmax = fmaxf(fmaxf(v[0], v[1]), fmaxf(v[2], v[3]));
      float tmin = fminf(fminf(v[0], v[1]), fminf(v[2], v[3]));
      mn_run[rr] = fminf(mn_run[rr], tmin);
      float mnew = fmaxf(m_run[rr], tmax);
      float s = 0.f;
#pragma unroll
      for (int nt = 0; nt < 4; ++nt) s += expf(v[nt] - mnew);
      l_run[rr] = l_run[rr] * expf(m_run[rr] - mnew) + s;
      m_run[rr] = mnew;
    }
  }
#pragma unroll
  for (int o = 1; o < 16; o <<= 1) {
#pragma unroll
    for (int rr = 0; rr < 4; ++rr) {
      float mo = __shfl_xor(m_run[rr], o);
      float lo = __shfl_xor(l_run[rr], o);
      float mnew = fmaxf(m_run[rr], mo);
      l_run[rr] = l_run[rr] * expf(m_run[rr] - mnew) + lo * expf(mo - mnew);
      m_run[rr] = mnew;
      mn_run[rr] = fminf(mn_run[rr], __shfl_xor(mn_run[rr], o));
    }
  }
  if (l16 == 0) {
    float cand = INFINITY;
#pragma unroll
    for (int rr = 0; rr < 4; ++rr) {
      int r = bh * 1024 + q0 + w * 16 + quad * 4 + rr;
      rmax[r] = m_run[rr];
      rsum[r] = l_run[rr];
      cand = fminf(cand, expf(mn_run[rr] - m_run[rr]) * (1.0f / l_run[rr]));
    }
    redmin[w * 4 + quad] = cand;
  }
  __syncthreads();
  if (t == 0) {
    float c = redmin[0];
#pragma unroll
    for (int i = 1; i < 16; ++i) c = fminf(c, redmin[i]);
    // candidates are strictly positive floats -> uint order == float order
    atomicMin(mnbits, __float_as_uint(c));
  }
}

// ------- pass 2: recompute QK^T (bitwise == pass 1), softmax+uns4, PV MFMA, sig8 -------
__global__ __launch_bounds__(256) void k_pv(
    const __bf16* kq, const __bf16* kkv,
    const float* rmax, const float* rsum,
    const float* mnf, const float* colsum, const __bf16* vt,
    const float* acq, const float* ack,
    const float* acattn, const float* acv, const float* ao,
    __bf16* ctxq) {
  __shared__ __align__(16) __bf16 Ks[64][AS];
  __shared__ __align__(16) __bf16 Vs[64][AS];
  __shared__ __align__(16) __bf16 As[32][AS];
  int bh = blockIdx.y;
  int m0 = blockIdx.x * 32;
  float mn    = mnf[0];                    // bits written by atomicMin = min float
  float a_att = fmaxf(acattn[0], EPSQ);
  float a_v   = fmaxf(acv[0], EPSQ);
  float a_o   = fmaxf(ao[0], EPSQ);
  float sc    = fmaxf(acq[0], EPSQ) * fmaxf(ack[0], EPSQ) * 0.125f;  // same as pass 1
  const __bf16* Qp = kq  + (size_t)bh * 65536;
  const __bf16* Kp = kkv + (size_t)bh * 65536;
  const __bf16* Vt = vt  + (size_t)bh * 65536;
  int t = threadIdx.x;
  int lane = t & 63, w = t >> 6, quad = lane >> 4, l16 = lane & 15;
  int e16 = (t & 3) * 16, mrow = t >> 2;
  int mt = w & 1, np = w >> 1;

  // Q fragments held in registers for the whole kernel (A-operand of QK^T)
  bf16x8 qa[2][2];
#pragma unroll
  for (int mh = 0; mh < 2; ++mh)
#pragma unroll
    for (int kh2 = 0; kh2 < 2; ++kh2)
      qa[mh][kh2] = *(const bf16x8*)&Qp[(size_t)(m0 + mh * 16 + l16) * 64 + kh2 * 32 + quad * 8];

  // row stats for the rows this thread produces in QK^T C-layout
  float rm[2][4], inv[2][4];
#pragma unroll
  for (int mh = 0; mh < 2; ++mh)
#pragma unroll
    for (int r = 0; r < 4; ++r) {
      int rr = bh * 1024 + m0 + mh * 16 + quad * 4 + r;
      rm[mh][r]  = rmax[rr];
      inv[mh][r] = 1.0f / rsum[rr];
    }

  floatx4 acc[2];
  acc[0] = (floatx4){0.f, 0.f, 0.f, 0.f};
  acc[1] = (floatx4){0.f, 0.f, 0.f, 0.f};

  pre2 kpre = ldb16(&Kp[(size_t)mrow * 64 + e16]);
  pre2 vpre = ldb16(&Vt[(size_t)mrow * 1024 + e16]);
  for (int ct = 0; ct < 16; ++ct) {
    if (ct) __syncthreads();
    stb16(&Ks[mrow][e16], kpre);
    stb16(&Vs[mrow][e16], vpre);
    if (ct < 15) {
      kpre = ldb16(&Kp[(size_t)((ct + 1) * 64 + mrow) * 64 + e16]);
      vpre = ldb16(&Vt[(size_t)mrow * 1024 + (ct + 1) * 64 + e16]);
    }
    __syncthreads();
    // QK^T: wave w owns k-cols ct*64 + w*16 + l16, rows m0..m0+31
    floatx4 s2[2];
    s2[0] = (floatx4){0.f, 0.f, 0.f, 0.f};
    s2[1] = (floatx4){0.f, 0.f, 0.f, 0.f};
#pragma unroll
    for (int kh2 = 0; kh2 < 2; ++kh2) {
      bf16x8 b = *(const bf16x8*)&Ks[w * 16 + l16][kh2 * 32 + quad * 8];
#pragma unroll
      for (int mh = 0; mh < 2; ++mh)
        s2[mh] = __builtin_amdgcn_mfma_f32_16x16x32_bf16(qa[mh][kh2], b, s2[mh], 0, 0, 0);
    }
    // softmax + uns4 quant -> LDS attn-levels tile (same arithmetic chain as pass 1)
#pragma unroll
    for (int mh = 0; mh < 2; ++mh)
#pragma unroll
      for (int r = 0; r < 4; ++r) {
        float p = expf(sc * s2[mh][r] - rm[mh][r]) * inv[mh][r];
        As[mh * 16 + quad * 4 + r][w * 16 + l16] =
            (__bf16)clampf(rintf((p - mn) / a_att), 0.f, 15.f);
      }
    __syncthreads();
    // PV
#pragma unroll
    for (int kh = 0; kh < 64; kh += 32) {
      bf16x8 a = *(const bf16x8*)&As[mt * 16 + l16][kh + quad * 8];
#pragma unroll
      for (int j = 0; j < 2; ++j) {
        bf16x8 b = *(const bf16x8*)&Vs[(np * 2 + j) * 16 + l16][kh + quad * 8];
        acc[j] = __builtin_amdgcn_mfma_f32_16x16x32_bf16(a, b, acc[j], 0, 0, 0);
      }
    }
  }
  float scf = a_att * a_v;
  float mnv = mn * a_v;
  int b = bh >> 3, h = bh & 7;
#pragma unroll
  for (int j = 0; j < 2; ++j) {
    int dd = (np * 2 + j) * 16 + l16;
    float cs = colsum[bh * 64 + dd];
#pragma unroll
    for (int r = 0; r < 4; ++r) {
      int srow = m0 + mt * 16 + quad * 4 + r;
      float ctx = scf * acc[j][r] + mnv * cs;
      float c8 = clampf(rintf(ctx / a_o), -128.f, 127.f);
      ctxq[(size_t)b * 524288 + (size_t)(h * 128 + (srow >> 3)) * 512 + (srow & 7) * 64 + dd] = (__bf16)c8;
    }
  }
}

// ---------------- output projection MFMA, pipelined ----------------
__global__ __launch_bounds__(256) void k_outg(
    const __bf16* ctxq, const __bf16* signs_o,
    const float* wabs_part, const float* ao, float* outb) {
  __shared__ __align__(16) __bf16 As[64][AS];
  __shared__ __align__(16) __bf16 Bs[64][AS];
  int n0 = blockIdx.x * 64, f0 = blockIdx.y * 64;
  int t = threadIdx.x;
  int lane = t & 63, w = t >> 6, quad = lane >> 4, l16 = lane & 15;
  int e16 = (t & 3) * 16, mrow = t >> 2;
  const __bf16* ap = &ctxq[(size_t)(n0 + mrow) * 512 + e16];
  const __bf16* bp = &signs_o[(size_t)(f0 + mrow) * 512 + e16];
  floatx4 acc[4];
#pragma unroll
  for (int nt = 0; nt < 4; ++nt) acc[nt] = (floatx4){0.f, 0.f, 0.f, 0.f};
  pre2 pa = ldb16(ap), pb = ldb16(bp);
  for (int k0 = 0; k0 < 512; k0 += 64) {
    if (k0) __syncthreads();
    stb16(&As[mrow][e16], pa);
    stb16(&Bs[mrow][e16], pb);
    if (k0 + 64 < 512) { pa = ldb16(ap + k0 + 64); pb = ldb16(bp + k0 + 64); }
    __syncthreads();
#pragma unroll
    for (int kh = 0; kh < 64; kh += 32) {
      bf16x8 a = *(const bf16x8*)&As[w * 16 + l16][kh + quad * 8];
#pragma unroll
      for (int nt = 0; nt < 4; ++nt) {
        bf16x8 b = *(const bf16x8*)&Bs[nt * 16 + l16][kh + quad * 8];
        acc[nt] = __builtin_amdgcn_mfma_f32_16x16x32_bf16(a, b, acc[nt], 0, 0, 0);
      }
    }
  }
  float sa = 0.f;
#pragma unroll
  for (int i = 0; i < 64; ++i) sa += wabs_part[3 * 64 + i];
  float scale = fmaxf(ao[0], EPSQ) * (sa * (1.0f / 262144.0f));
#pragma unroll
  for (int nt = 0; nt < 4; ++nt)
#pragma unroll
    for (int r = 0; r < 4; ++r)
      outb[(size_t)(n0 + w * 16 + quad * 4 + r) * 512 + f0 + nt * 16 + l16] = scale * acc[nt][r];
}

// ---------------- layernorm(q + out) -> output 0 ----------------
__global__ __launch_bounds__(256) void k_ln(
    const float* q, const float* outb, const float* g, const float* bb, float* out0) {
  __shared__ float red[256];
  int r = blockIdx.x, t = threadIdx.x;
  const float* qp = q + (size_t)r * 512;
  const float* op = outb + (size_t)r * 512;
  float y0 = qp[t] + op[t];
  float y1 = qp[t + 256] + op[t + 256];
  red[t] = y0 + y1; __syncthreads();
  for (int o = 128; o > 0; o >>= 1) { if (t < o) red[t] += red[t + o]; __syncthreads(); }
  float mu = red[0] * (1.0f / 512.0f); __syncthreads();
  float d0 = y0 - mu, d1 = y1 - mu;
  red[t] = d0 * d0 + d1 * d1; __syncthreads();
  for (int o = 128; o > 0; o >>= 1) { if (t < o) red[t] += red[t + o]; __syncthreads(); }
  float var = red[0] * (1.0f / 512.0f);
  float den = sqrtf(var + 1e-5f);
  out0[(size_t)r * 512 + t]       = d0 / den * g[t] + bb[t];
  out0[(size_t)r * 512 + t + 256] = d1 / den * g[t + 256] + bb[t + 256];
}

extern "C" void kernel_launch(void* const* d_in, const int* in_sizes, int n_in,
                              void* d_out, int out_size, void* d_ws, size_t ws_size,
                              hipStream_t stream) {
  const float* q   = (const float*)d_in[0];
  const float* k   = (const float*)d_in[1];
  const float* v   = (const float*)d_in[2];
  // d_in[3] = mask (int32) — structurally unused by the reference
  const float* Wq  = (const float*)d_in[4];
  const float* Wk  = (const float*)d_in[5];
  const float* Wv  = (const float*)d_in[6];
  const float* Wo  = (const float*)d_in[7];
  const float* bq  = (const float*)d_in[8];
  const float* bk  = (const float*)d_in[9];
  const float* bv  = (const float*)d_in[10];
  const float* lng = (const float*)d_in[11];
  const float* lnb = (const float*)d_in[12];
  const float* aq  = (const float*)d_in[13];
  const float* ak  = (const float*)d_in[14];
  const float* av  = (const float*)d_in[15];
  const float* acq = (const float*)d_in[16];
  const float* ack = (const float*)d_in[17];
  const float* acv = (const float*)d_in[18];
  const float* aca = (const float*)d_in[19];
  const float* ao  = (const float*)d_in[20];

  char* ws = (char*)d_ws;
  float*  wsum_p = (float*)(ws + O_WSUMP);
  float*  wabs_p = (float*)(ws + O_WABSP);
  float*  mnf    = (float*)(ws + O_MN);
  float*  colsum = (float*)(ws + O_COLSUM);
  __bf16* wsigns = (__bf16*)(ws + O_WSIGNS);
  __bf16* qlv    = (__bf16*)(ws + O_QLV);
  __bf16* klv    = (__bf16*)(ws + O_KLV);
  __bf16* vlv    = (__bf16*)(ws + O_VLV);
  __bf16* kqb    = (__bf16*)(ws + O_KQ);
  __bf16* kkb    = (__bf16*)(ws + O_KK);
  __bf16* vtb    = (__bf16*)(ws + O_VT);
  float*  rmax   = (float*)(ws + O_RMAX);
  float*  rsum   = (float*)(ws + O_RSUM);
  __bf16* ctxq   = (__bf16*)(ws + O_CTXQ);
  float*  outb   = (float*)(ws + O_OUTB);

  float* out0   = (float*)d_out;
  float* scores = (float*)d_out + OUT0N;

  k_wstats<<<256, 256, 0, stream>>>(Wq, Wk, Wv, Wo, wsum_p, wabs_p, colsum,
                                    (unsigned int*)mnf);
  k_signqx<<<dim3(1024, 4), 256, 0, stream>>>(Wq, Wk, Wv, Wo, wsum_p,
                                              q, k, v, aq, ak, av,
                                              wsigns, qlv, klv, vlv);
  k_proj<<<dim3(64, 8, 3), 256, 0, stream>>>(qlv, klv, vlv, bq, bk, bv, aq, ak, av,
                                             acq, ack, acv, wsigns, wabs_p,
                                             kqb, kkb, vtb, colsum);
  k_qks<<<dim3(16, 32), 256, 0, stream>>>(kqb, kkb, acq, ack, scores, rmax, rsum,
                                          (unsigned int*)mnf);
  k_pv<<<dim3(32, 32), 256, 0, stream>>>(kqb, kkb, rmax, rsum, mnf, colsum, vtb,
                                         acq, ack, aca, acv, ao, ctxq);
  k_outg<<<dim3(64, 8), 256, 0, stream>>>(ctxq, wsigns + 3 * WELEM, wabs_p, ao, outb);
  k_ln<<<4096, 256, 0, stream>>>(q, outb, lng, lnb, out0);
}